// Round 15
// baseline (204.485 us; speedup 1.0000x reference)
//
#include <hip/hip_runtime.h>
#include <hip/hip_bf16.h>
#include <hip/hip_fp16.h>
#include <math.h>

// ---------------------------------------------------------------------------
// GATv2 x2 + log_softmax + gated rule-net.
// R14: (a) head-phasing REVERTED (FETCH rose -- refuted); (b) per-row
// SRC-SORTED adjacency: all agg groups co-resident sweep sorted lists in
// near-lockstep -> instantaneous gather working set ~2.6MB < 4MB/XCD L2
// (was 12.8MB random). Sort done in build_scatter's LDS (insertion sort per
// row, ~17 elems). (c) pairs packed to uint32 (src<<9 | dst&511).
// ---------------------------------------------------------------------------

typedef _Float16 h2 __attribute__((ext_vector_type(2)));
typedef _Float16 half8_t __attribute__((ext_vector_type(8)));
typedef float f32x4_t __attribute__((ext_vector_type(4)));
union H2U { unsigned int u; h2 h; };
__device__ inline h2 bch2(unsigned int x) { H2U t; t.u = x; return t.h; }

constexpr int BKT_W = 512;   // dsts per bucket
constexpr int PA_EPT = 8;    // edges per thread, bucket_pass
constexpr int LCAP = 12288;  // LDS srcs capacity per bucket (48 KB)

__device__ inline float dpp_xor1(float x) {
    int v = __builtin_amdgcn_mov_dpp(__builtin_bit_cast(int, x), 0xB1, 0xF, 0xF, true);
    return __builtin_bit_cast(float, v);
}
__device__ inline float dpp_xor2(float x) {
    int v = __builtin_amdgcn_mov_dpp(__builtin_bit_cast(int, x), 0x4E, 0xF, 0xF, true);
    return __builtin_bit_cast(float, v);
}

__global__ void fill_int_kernel(int* __restrict__ p, int v, int count) {
    int i = blockIdx.x * blockDim.x + threadIdx.x;
    if (i < count) p[i] = v;
}

// A1: edges-per-bucket histogram (LDS, one global atomic per block-bin)
__global__ __launch_bounds__(1024)
void bkt_hist_kernel(const int* __restrict__ ei, int* __restrict__ ecnt, int E, int nb) {
    __shared__ int lh[128];
    if (threadIdx.x < 128) lh[threadIdx.x] = 0;
    __syncthreads();
    for (int e = blockIdx.x * blockDim.x + threadIdx.x; e < E; e += gridDim.x * blockDim.x)
        atomicAdd(&lh[ei[E + e] >> 9], 1);
    __syncthreads();
    if (threadIdx.x < (unsigned)nb && lh[threadIdx.x])
        atomicAdd(&ecnt[threadIdx.x], lh[threadIdx.x]);
}

// A2: exclusive scan of <=128 bucket counts -> ebase; seed bcur.
__global__ __launch_bounds__(128)
void bkt_scan_kernel(const int* __restrict__ ecnt, int* __restrict__ ebase,
                     int* __restrict__ bcur, int nb) {
    __shared__ int s[128];
    int t = threadIdx.x;
    int v = (t < nb) ? ecnt[t] : 0;
    s[t] = v;
    __syncthreads();
    #pragma unroll
    for (int off = 1; off < 128; off <<= 1) {
        int u = (t >= off) ? s[t - off] : 0;
        __syncthreads();
        s[t] += u;
        __syncthreads();
    }
    if (t < nb) { int b = s[t] - v; ebase[t] = b; bcur[t] = b; }
}

// A3: partition edges into buckets (LDS ranks); pairs packed src<<9 | dst&511.
__global__ __launch_bounds__(1024)
void bucket_pass_kernel(const int* __restrict__ ei, int E,
                        int* __restrict__ bcur, unsigned* __restrict__ pairs, int nb) {
    __shared__ int lhist[128];
    __shared__ int lbase[128];
    int e0 = blockIdx.x * (1024 * PA_EPT);
    if (threadIdx.x < 128) lhist[threadIdx.x] = 0;
    __syncthreads();
    int mysrc[PA_EPT], mydst[PA_EPT], myrank[PA_EPT];
    #pragma unroll
    for (int j = 0; j < PA_EPT; j++) {
        int e = e0 + j * 1024 + threadIdx.x;
        if (e < E) {
            mysrc[j] = ei[e];
            mydst[j] = ei[E + e];
            myrank[j] = atomicAdd(&lhist[mydst[j] >> 9], 1);
        } else mydst[j] = -1;
    }
    __syncthreads();
    if (threadIdx.x < (unsigned)nb && lhist[threadIdx.x] > 0)
        lbase[threadIdx.x] = atomicAdd(&bcur[threadIdx.x], lhist[threadIdx.x]);
    __syncthreads();
    #pragma unroll
    for (int j = 0; j < PA_EPT; j++) {
        if (mydst[j] >= 0) {
            int b = mydst[j] >> 9;
            pairs[(size_t)lbase[b] + myrank[j]] =
                ((unsigned)mysrc[j] << 9) | (unsigned)(mydst[j] & 511);
        }
    }
}

// B: one block per bucket: LDS hist -> scan -> rowptr; scatter into LDS,
// insertion-sort each row (src ascending, self-loop included), coalesced
// writeback. Fallback to unsorted global path if bucket overflows LCAP.
__global__ __launch_bounds__(512)
void build_scatter_kernel(const unsigned* __restrict__ pairs, const int* __restrict__ ecnt,
                          const int* __restrict__ ebase,
                          int* __restrict__ rowptr, int* __restrict__ srcs, int n, int nb) {
    __shared__ int lcnt[BKT_W];
    __shared__ int ssc[BKT_W];
    __shared__ int cur[BKT_W];
    __shared__ int lsrc[LCAP];
    int b = blockIdx.x;
    int lo = b * BKT_W;
    int hi = min(lo + BKT_W, n);
    int nrows = hi - lo;
    int cnt = ecnt[b], base = ebase[b];
    int s0 = base + lo;            // global srcs start of this bucket's segment
    int total = cnt + nrows;
    int t = threadIdx.x;
    lcnt[t] = 0;
    __syncthreads();
    for (int k = base + t; k < base + cnt; k += 512)
        atomicAdd(&lcnt[pairs[k] & 511u], 1);
    __syncthreads();
    int myc = lcnt[t];
    ssc[t] = myc;
    __syncthreads();
    #pragma unroll
    for (int off = 1; off < 512; off <<= 1) {
        int u = (t >= off) ? ssc[t - off] : 0;
        __syncthreads();
        ssc[t] += u;
        __syncthreads();
    }
    int lstart = (ssc[t] - myc) + t;   // bucket-local row start (edges + prior self-loops)
    if (t < nrows) rowptr[lo + t] = s0 + lstart;
    if (b == nb - 1 && t == 0) rowptr[n] = s0 + total;
    if (total <= LCAP) {
        if (t < nrows) { lsrc[lstart] = lo + t; cur[t] = lstart + 1; }
        __syncthreads();
        for (int k = base + t; k < base + cnt; k += 512) {
            unsigned pr = pairs[k];
            int pos = atomicAdd(&cur[pr & 511u], 1);
            lsrc[pos] = (int)(pr >> 9);
        }
        __syncthreads();
        if (t < nrows) {            // insertion sort this row in LDS
            int st = lstart, en = lstart + 1 + myc;
            for (int i = st + 1; i < en; i++) {
                int v = lsrc[i];
                int j = i - 1;
                while (j >= st && lsrc[j] > v) { lsrc[j + 1] = lsrc[j]; j--; }
                lsrc[j + 1] = v;
            }
        }
        __syncthreads();
        for (int k = t; k < total; k += 512) srcs[s0 + k] = lsrc[k];
    } else {                        // overflow fallback: unsorted, direct global
        if (t < nrows) { srcs[s0 + lstart] = lo + t; cur[t] = s0 + lstart + 1; }
        __syncthreads();
        for (int k = base + t; k < base + cnt; k += 512) {
            unsigned pr = pairs[k];
            int pos = atomicAdd(&cur[pr & 511u], 1);
            srcs[pos] = (int)(pr >> 9);
        }
    }
}

// Pack weights into MFMA B-frag layout (16x16x32 f16) -- device body
template<int NC, int K, bool DUAL>
__device__ inline void pack_w_dev(const float* __restrict__ W0, const float* __restrict__ W1,
                                  __half* __restrict__ Wp, int blk) {
    constexpr int KC = K / 32;
    constexpr int M = DUAL ? NC / 2 : NC;
    int idx = blk * 256 + (int)threadIdx.x;
    if (idx >= (NC / 16) * KC * 64) return;
    int lane = idx & 63;
    int c = (idx >> 6) % KC;
    int t = idx / (64 * KC);
    int col = t * 16 + (lane & 15);
    int k0 = c * 32 + (lane >> 4) * 8;
    __half tmp[8];
    #pragma unroll
    for (int e = 0; e < 8; e++) {
        int k = k0 + e;
        float v;
        if (DUAL) v = (col < M) ? W0[(size_t)k * M + col] : W1[(size_t)k * M + (col - M)];
        else      v = W0[(size_t)k * M + col];
        tmp[e] = __float2half(v);
    }
    *(uint4*)(Wp + (size_t)idx * 8) = *(uint4*)tmp;
}

// All 4 weight packs in one launch.
__global__ __launch_bounds__(256)
void pack_all_kernel(const float* __restrict__ Wl1, const float* __restrict__ Wr1,
                     const float* __restrict__ Wl2, const float* __restrict__ Wr2,
                     const float* __restrict__ We1, const float* __restrict__ We2,
                     __half* __restrict__ Wp1, __half* __restrict__ Wp2,
                     __half* __restrict__ We1p, __half* __restrict__ We2p) {
    int b = blockIdx.x;
    if (b < 16)      pack_w_dev<256, 128, true>(Wl1, Wr1, Wp1, b);
    else if (b < 24) pack_w_dev<128, 128, true>(Wl2, Wr2, Wp2, b - 16);
    else if (b < 26) pack_w_dev<64, 64, false>(We1, nullptr, We1p, b - 24);
    else             pack_w_dev<64, 64, false>(We2, nullptr, We2p, b - 26);
}

__device__ inline half8_t load_a8(const __half* p) { return *(const half8_t*)p; }
__device__ inline half8_t load_a8(const float* p) {
    float4 v0 = *(const float4*)p;
    float4 v1 = *(const float4*)(p + 4);
    half8_t r;
    r[0] = (_Float16)v0.x; r[1] = (_Float16)v0.y; r[2] = (_Float16)v0.z; r[3] = (_Float16)v0.w;
    r[4] = (_Float16)v1.x; r[5] = (_Float16)v1.y; r[6] = (_Float16)v1.z; r[7] = (_Float16)v1.w;
    return r;
}

// MFMA dual GEMM: one wave per (16-row tile, col quarter); no LDS.
template<int NC, int K, typename AT>
__global__ __launch_bounds__(256)
void gemm_mfma_kernel(const AT* __restrict__ A, const __half* __restrict__ Wp,
                      __half* __restrict__ Y0, __half* __restrict__ Y1, int n) {
    constexpr int KC = K / 32;
    constexpr int NT = NC / 16;
    constexpr int NTW = NT / 4;
    constexpr int M = NC / 2;
    int gw = (int)((blockIdx.x * 256 + threadIdx.x) >> 6);
    int lane = threadIdx.x & 63;
    int rt = gw >> 2;
    int wq = gw & 3;
    int row0 = rt * 16;
    if (row0 >= n) return;
    int arow = row0 + (lane & 15);
    int koff = (lane >> 4) * 8;
    half8_t af[KC];
    #pragma unroll
    for (int c = 0; c < KC; c++) {
        af[c] = (arow < n) ? load_a8(A + (size_t)arow * K + c * 32 + koff)
                           : half8_t{0, 0, 0, 0, 0, 0, 0, 0};
    }
    #pragma unroll
    for (int t4 = 0; t4 < NTW; t4++) {
        int t = wq * NTW + t4;
        f32x4_t acc = {0.f, 0.f, 0.f, 0.f};
        #pragma unroll
        for (int c = 0; c < KC; c++) {
            half8_t bf = *(const half8_t*)(Wp + (((size_t)t * KC + c) * 64 + lane) * 8);
            acc = __builtin_amdgcn_mfma_f32_16x16x32_f16(af[c], bf, acc, 0, 0, 0);
        }
        int col = t * 16 + (lane & 15);
        #pragma unroll
        for (int r = 0; r < 4; r++) {
            int row = row0 + (lane >> 4) * 4 + r;
            if (row < n) {
                __half v = __float2half(acc[r]);
                if (col < M) Y0[(size_t)row * M + col] = v;
                else         Y1[(size_t)row * M + (col - M)] = v;
            }
        }
    }
}

// 4 lanes per (node, head), heads interleaved (g%H). Single pass, DPP quad
// reduce, exp without max-subtraction. LS_MODE (H=1) fuses log_softmax.
// srcs are per-row SORTED ascending -> co-resident groups sweep the table
// in near-lockstep (L2-resident moving window).
template<int H, bool LS_MODE>
__global__ __launch_bounds__(256)
void node_agg_kernel(const __half* __restrict__ xl, const __half* __restrict__ xr,
                     const int* __restrict__ rowptr, const int* __restrict__ srcs,
                     const float* __restrict__ att, const float* __restrict__ bias,
                     __half* __restrict__ outh, float* __restrict__ outf, int n) {
    constexpr int HC = 64 * H;
    int g = (blockIdx.x * blockDim.x + threadIdx.x) >> 2;
    int lane = threadIdx.x & 3;
    if (g >= n * H) return;
    int node = g / H, head = g % H;
    int cb = head * 64 + lane * 16;

    const __half* xrp = xr + (size_t)node * HC + cb;
    uint4 ur0 = *(const uint4*)(xrp);
    uint4 ur1 = *(const uint4*)(xrp + 8);
    h2 r[8] = {bch2(ur0.x), bch2(ur0.y), bch2(ur0.z), bch2(ur0.w),
               bch2(ur1.x), bch2(ur1.y), bch2(ur1.z), bch2(ur1.w)};
    const float* ap = att + cb;
    h2 a[8];
    #pragma unroll
    for (int j = 0; j < 8; j++)
        a[j] = h2{(_Float16)ap[2 * j], (_Float16)ap[2 * j + 1]};
    const h2 k02 = {(_Float16)0.2f, (_Float16)0.2f};

    int start = rowptr[node], end = rowptr[node + 1];
    float d = 0.f;
    float acc[16];
    #pragma unroll
    for (int j = 0; j < 16; j++) acc[j] = 0.f;

    #pragma unroll 2
    for (int k = start; k < end; ++k) {
        int src = srcs[k];
        const __half* xlp = xl + (size_t)src * HC + cb;
        uint4 u0 = *(const uint4*)(xlp);
        uint4 u1 = *(const uint4*)(xlp + 8);
        h2 l[8] = {bch2(u0.x), bch2(u0.y), bch2(u0.z), bch2(u0.w),
                   bch2(u1.x), bch2(u1.y), bch2(u1.z), bch2(u1.w)};
        float pa = 0.f, pb = 0.f;
        #pragma unroll
        for (int j = 0; j < 4; j++) {
            h2 s = l[j] + r[j];
            s = __builtin_elementwise_max(s, s * k02);   // leaky_relu
            pa = __builtin_amdgcn_fdot2(s, a[j], pa, false);
        }
        #pragma unroll
        for (int j = 4; j < 8; j++) {
            h2 s = l[j] + r[j];
            s = __builtin_elementwise_max(s, s * k02);
            pb = __builtin_amdgcn_fdot2(s, a[j], pb, false);
        }
        float p = pa + pb;
        p += dpp_xor1(p);
        p += dpp_xor2(p);          // quad holds the head's logit
        float w = __expf(p);
        d += w;
        #pragma unroll
        for (int j = 0; j < 8; j++) {
            acc[2 * j]     += w * (float)l[j][0];
            acc[2 * j + 1] += w * (float)l[j][1];
        }
    }

    float inv = 1.f / (d + 1e-16f);
    const float* bp = bias + cb;
    if (!LS_MODE) {
        float o[16];
        #pragma unroll
        for (int j = 0; j < 16; j++) o[j] = fmaxf(acc[j] * inv + bp[j], 0.f);
        __half* op = outh + (size_t)node * HC + cb;
        uint4 w0, w1;
        __half2 t0 = __floats2half2_rn(o[0], o[1]),  t1 = __floats2half2_rn(o[2], o[3]);
        __half2 t2 = __floats2half2_rn(o[4], o[5]),  t3 = __floats2half2_rn(o[6], o[7]);
        __half2 t4 = __floats2half2_rn(o[8], o[9]),  t5 = __floats2half2_rn(o[10], o[11]);
        __half2 t6 = __floats2half2_rn(o[12], o[13]), t7 = __floats2half2_rn(o[14], o[15]);
        w0.x = *(unsigned int*)&t0; w0.y = *(unsigned int*)&t1;
        w0.z = *(unsigned int*)&t2; w0.w = *(unsigned int*)&t3;
        w1.x = *(unsigned int*)&t4; w1.y = *(unsigned int*)&t5;
        w1.z = *(unsigned int*)&t6; w1.w = *(unsigned int*)&t7;
        *(uint4*)(op) = w0;
        *(uint4*)(op + 8) = w1;
    } else {
        float v[16];
        #pragma unroll
        for (int j = 0; j < 16; j++) v[j] = acc[j] * inv + bp[j];
        float m = v[0];
        #pragma unroll
        for (int j = 1; j < 16; j++) m = fmaxf(m, v[j]);
        m = fmaxf(m, dpp_xor1(m));
        m = fmaxf(m, dpp_xor2(m));
        float s = 0.f;
        #pragma unroll
        for (int j = 0; j < 16; j++) s += __expf(v[j] - m);
        s += dpp_xor1(s);
        s += dpp_xor2(s);
        float lg = __logf(s);
        float ls[16];
        #pragma unroll
        for (int j = 0; j < 16; j++) ls[j] = v[j] - m - lg;
        float* of = outf + (size_t)node * HC + cb;
        #pragma unroll
        for (int q = 0; q < 4; q++)
            *(float4*)(of + q * 4) = make_float4(ls[q * 4], ls[q * 4 + 1], ls[q * 4 + 2], ls[q * 4 + 3]);
        __half* op = outh + (size_t)node * HC + cb;
        uint4 w0, w1;
        __half2 t0 = __floats2half2_rn(ls[0], ls[1]),  t1 = __floats2half2_rn(ls[2], ls[3]);
        __half2 t2 = __floats2half2_rn(ls[4], ls[5]),  t3 = __floats2half2_rn(ls[6], ls[7]);
        __half2 t4 = __floats2half2_rn(ls[8], ls[9]),  t5 = __floats2half2_rn(ls[10], ls[11]);
        __half2 t6 = __floats2half2_rn(ls[12], ls[13]), t7 = __floats2half2_rn(ls[14], ls[15]);
        w0.x = *(unsigned int*)&t0; w0.y = *(unsigned int*)&t1;
        w0.z = *(unsigned int*)&t2; w0.w = *(unsigned int*)&t3;
        w1.x = *(unsigned int*)&t4; w1.y = *(unsigned int*)&t5;
        w1.z = *(unsigned int*)&t6; w1.w = *(unsigned int*)&t7;
        *(uint4*)(op) = w0;
        *(uint4*)(op + 8) = w1;
    }
}

// Fused rule-net: T = relu(LS@We1+be1) (MFMA via LDS fp16 transpose),
// G = T@We2+be2, out = ls + sigmoid(G).
__global__ __launch_bounds__(256)
void gate_kernel(const float* __restrict__ lsf, const __half* __restrict__ lsh,
                 const __half* __restrict__ We1p, const float* __restrict__ be1,
                 const __half* __restrict__ We2p, const float* __restrict__ be2,
                 float* __restrict__ out, int n) {
    __shared__ _Float16 tls[4][16][64];
    int wid = threadIdx.x >> 6, lane = threadIdx.x & 63;
    int row0 = (blockIdx.x * 4 + wid) * 16;
    if (row0 >= n) return;
    int arow = row0 + (lane & 15);
    int koff = (lane >> 4) * 8;
    int colw = lane & 15;
    int rbase = (lane >> 4) * 4;

    half8_t af0 = (arow < n) ? *(const half8_t*)(lsh + (size_t)arow * 64 + koff)
                             : half8_t{0, 0, 0, 0, 0, 0, 0, 0};
    half8_t af1 = (arow < n) ? *(const half8_t*)(lsh + (size_t)arow * 64 + 32 + koff)
                             : half8_t{0, 0, 0, 0, 0, 0, 0, 0};
    #pragma unroll
    for (int t = 0; t < 4; t++) {
        f32x4_t acc = {0.f, 0.f, 0.f, 0.f};
        half8_t b0 = *(const half8_t*)(We1p + (((size_t)t * 2 + 0) * 64 + lane) * 8);
        half8_t b1 = *(const half8_t*)(We1p + (((size_t)t * 2 + 1) * 64 + lane) * 8);
        acc = __builtin_amdgcn_mfma_f32_16x16x32_f16(af0, b0, acc, 0, 0, 0);
        acc = __builtin_amdgcn_mfma_f32_16x16x32_f16(af1, b1, acc, 0, 0, 0);
        float bv = be1[t * 16 + colw];
        #pragma unroll
        for (int r = 0; r < 4; r++)
            tls[wid][rbase + r][t * 16 + colw] = (_Float16)fmaxf(acc[r] + bv, 0.f);
    }
    half8_t tf0 = *(const half8_t*)&tls[wid][lane & 15][koff];
    half8_t tf1 = *(const half8_t*)&tls[wid][lane & 15][32 + koff];
    #pragma unroll
    for (int t = 0; t < 4; t++) {
        f32x4_t acc = {0.f, 0.f, 0.f, 0.f};
        half8_t b0 = *(const half8_t*)(We2p + (((size_t)t * 2 + 0) * 64 + lane) * 8);
        half8_t b1 = *(const half8_t*)(We2p + (((size_t)t * 2 + 1) * 64 + lane) * 8);
        acc = __builtin_amdgcn_mfma_f32_16x16x32_f16(tf0, b0, acc, 0, 0, 0);
        acc = __builtin_amdgcn_mfma_f32_16x16x32_f16(tf1, b1, acc, 0, 0, 0);
        int col = t * 16 + colw;
        float bv = be2[col];
        #pragma unroll
        for (int r = 0; r < 4; r++) {
            int row = row0 + rbase + r;
            if (row < n) {
                float g = 1.f / (1.f + __expf(-(acc[r] + bv)));
                out[(size_t)row * 64 + col] = lsf[(size_t)row * 64 + col] + g;
            }
        }
    }
}

extern "C" void kernel_launch(void* const* d_in, const int* in_sizes, int n_in,
                              void* d_out, int out_size, void* d_ws, size_t ws_size,
                              hipStream_t stream) {
    const float* x    = (const float*)d_in[0];
    const int*   ei   = (const int*)d_in[1];
    const float* Wl1  = (const float*)d_in[2];
    const float* Wr1  = (const float*)d_in[3];
    const float* att1 = (const float*)d_in[4];
    const float* b1   = (const float*)d_in[5];
    const float* Wl2  = (const float*)d_in[6];
    const float* Wr2  = (const float*)d_in[7];
    const float* att2 = (const float*)d_in[8];
    const float* b2   = (const float*)d_in[9];
    const float* We1  = (const float*)d_in[10];
    const float* be1  = (const float*)d_in[11];
    const float* We2  = (const float*)d_in[12];
    const float* be2  = (const float*)d_in[13];
    float* out = (float*)d_out;

    const int n  = in_sizes[0] / 128;
    const int E  = in_sizes[1] / 2;
    const int ET = E + n;
    const int nb = (n + BKT_W - 1) / BKT_W;

    float* ws = (float*)d_ws;
    size_t o = 0;
    __half* xl1 = (__half*)(ws + o); o += (size_t)n * 64;   // [n,128] fp16
    __half* xr1 = (__half*)(ws + o); o += (size_t)n * 64;   // [n,128] fp16
    __half* h1h = (__half*)(ws + o); o += (size_t)n * 64;   // h1 fp16 [n,128]
    float*  v2  = ws + o;            o += (size_t)n * 64;   // ls fp32 [n,64]
    __half* lsh = (__half*)(ws + o); o += (size_t)n * 32;   // ls fp16 [n,64]
    __half* Wp1 = (__half*)(ws + o); o += 16384;
    __half* Wp2 = (__half*)(ws + o); o += 8192;
    __half* We1p = (__half*)(ws + o); o += 2048;
    __half* We2p = (__half*)(ws + o); o += 2048;
    int* rowptr   = (int*)(ws + o); o += (size_t)(n + 1);
    int* srcs     = (int*)(ws + o); o += (size_t)ET;
    unsigned* pairs = (unsigned*)(ws + o); o += (size_t)E;  // packed src<<9|dstlo
    int* ecnt     = (int*)(ws + o); o += 128;
    int* ebase    = (int*)(ws + o); o += 128;
    int* bcur     = (int*)(ws + o); o += 128;
    __half* xl2 = xl1;                     // [n,64] fp16 (reuses dead xl1 region)
    __half* xr2 = xl1 + (size_t)n * 64;
    float* lsf = v2;

    const int BS = 256;
    auto blocks = [](long long t, int bs) { return (int)((t + bs - 1) / bs); };

    // ---- CSR build (by dst), atomic-free per node, per-row src-sorted ----
    fill_int_kernel<<<1, 128, 0, stream>>>(ecnt, 0, 128);
    bkt_hist_kernel<<<128, 1024, 0, stream>>>(ei, ecnt, E, nb);
    bkt_scan_kernel<<<1, 128, 0, stream>>>(ecnt, ebase, bcur, nb);
    bucket_pass_kernel<<<blocks(E, 1024 * PA_EPT), 1024, 0, stream>>>(ei, E, bcur, pairs, nb);
    build_scatter_kernel<<<nb, 512, 0, stream>>>(pairs, ecnt, ebase, rowptr, srcs, n, nb);

    // ---- all weight packs, one launch ----
    pack_all_kernel<<<28, 256, 0, stream>>>(Wl1, Wr1, Wl2, Wr2, We1, We2,
                                            Wp1, Wp2, We1p, We2p);

    // ---- layer 1 (gemm reads fp32 x directly) ----
    const int rt = (n + 15) / 16;          // row tiles
    gemm_mfma_kernel<256, 128, float><<<rt, 256, 0, stream>>>(x, Wp1, xl1, xr1, n);
    node_agg_kernel<2, false><<<blocks((long long)n * 2 * 4, BS), BS, 0, stream>>>(
        xl1, xr1, rowptr, srcs, att1, b1, h1h, nullptr, n);

    // ---- layer 2 (log_softmax fused into agg) ----
    gemm_mfma_kernel<128, 128, __half><<<rt, 256, 0, stream>>>(h1h, Wp2, xl2, xr2, n);
    node_agg_kernel<1, true><<<blocks((long long)n * 4, BS), BS, 0, stream>>>(
        xl2, xr2, rowptr, srcs, att2, b2, lsh, v2, n);

    // ---- finalize: fused MFMA rule-net ----
    gate_kernel<<<(n + 63) / 64, BS, 0, stream>>>(lsf, lsh, We1p, be1, We2p, be2, out, n);
}

// Round 16
// 172.043 us; speedup vs baseline: 1.1886x; 1.1886x over previous
//
#include <hip/hip_runtime.h>
#include <hip/hip_bf16.h>
#include <hip/hip_fp16.h>
#include <math.h>

// ---------------------------------------------------------------------------
// GATv2 x2 + log_softmax + gated rule-net.
// R15: sorted adjacency KEPT (R14 proved ~20us agg gain) but sort moved out
// of build_scatter (65us LDS insertion sort, 6% occupancy) into a dedicated
// wave-per-row register bitonic sort via shfl_xor (~5us, full occupancy).
// build_scatter reverted to R13's fast direct-global form.
// ---------------------------------------------------------------------------

typedef _Float16 h2 __attribute__((ext_vector_type(2)));
typedef _Float16 half8_t __attribute__((ext_vector_type(8)));
typedef float f32x4_t __attribute__((ext_vector_type(4)));
union H2U { unsigned int u; h2 h; };
__device__ inline h2 bch2(unsigned int x) { H2U t; t.u = x; return t.h; }

constexpr int BKT_W = 512;   // dsts per bucket
constexpr int PA_EPT = 8;    // edges per thread, bucket_pass

__device__ inline float dpp_xor1(float x) {
    int v = __builtin_amdgcn_mov_dpp(__builtin_bit_cast(int, x), 0xB1, 0xF, 0xF, true);
    return __builtin_bit_cast(float, v);
}
__device__ inline float dpp_xor2(float x) {
    int v = __builtin_amdgcn_mov_dpp(__builtin_bit_cast(int, x), 0x4E, 0xF, 0xF, true);
    return __builtin_bit_cast(float, v);
}

__global__ void fill_int_kernel(int* __restrict__ p, int v, int count) {
    int i = blockIdx.x * blockDim.x + threadIdx.x;
    if (i < count) p[i] = v;
}

// A1: edges-per-bucket histogram (LDS, one global atomic per block-bin)
__global__ __launch_bounds__(1024)
void bkt_hist_kernel(const int* __restrict__ ei, int* __restrict__ ecnt, int E, int nb) {
    __shared__ int lh[128];
    if (threadIdx.x < 128) lh[threadIdx.x] = 0;
    __syncthreads();
    for (int e = blockIdx.x * blockDim.x + threadIdx.x; e < E; e += gridDim.x * blockDim.x)
        atomicAdd(&lh[ei[E + e] >> 9], 1);
    __syncthreads();
    if (threadIdx.x < (unsigned)nb && lh[threadIdx.x])
        atomicAdd(&ecnt[threadIdx.x], lh[threadIdx.x]);
}

// A2: exclusive scan of <=128 bucket counts -> ebase; seed bcur.
__global__ __launch_bounds__(128)
void bkt_scan_kernel(const int* __restrict__ ecnt, int* __restrict__ ebase,
                     int* __restrict__ bcur, int nb) {
    __shared__ int s[128];
    int t = threadIdx.x;
    int v = (t < nb) ? ecnt[t] : 0;
    s[t] = v;
    __syncthreads();
    #pragma unroll
    for (int off = 1; off < 128; off <<= 1) {
        int u = (t >= off) ? s[t - off] : 0;
        __syncthreads();
        s[t] += u;
        __syncthreads();
    }
    if (t < nb) { int b = s[t] - v; ebase[t] = b; bcur[t] = b; }
}

// A3: partition edges into buckets (LDS ranks); pairs packed src<<9 | dst&511.
__global__ __launch_bounds__(1024)
void bucket_pass_kernel(const int* __restrict__ ei, int E,
                        int* __restrict__ bcur, unsigned* __restrict__ pairs, int nb) {
    __shared__ int lhist[128];
    __shared__ int lbase[128];
    int e0 = blockIdx.x * (1024 * PA_EPT);
    if (threadIdx.x < 128) lhist[threadIdx.x] = 0;
    __syncthreads();
    int mysrc[PA_EPT], mydst[PA_EPT], myrank[PA_EPT];
    #pragma unroll
    for (int j = 0; j < PA_EPT; j++) {
        int e = e0 + j * 1024 + threadIdx.x;
        if (e < E) {
            mysrc[j] = ei[e];
            mydst[j] = ei[E + e];
            myrank[j] = atomicAdd(&lhist[mydst[j] >> 9], 1);
        } else mydst[j] = -1;
    }
    __syncthreads();
    if (threadIdx.x < (unsigned)nb && lhist[threadIdx.x] > 0)
        lbase[threadIdx.x] = atomicAdd(&bcur[threadIdx.x], lhist[threadIdx.x]);
    __syncthreads();
    #pragma unroll
    for (int j = 0; j < PA_EPT; j++) {
        if (mydst[j] >= 0) {
            int b = mydst[j] >> 9;
            pairs[(size_t)lbase[b] + myrank[j]] =
                ((unsigned)mysrc[j] << 9) | (unsigned)(mydst[j] & 511);
        }
    }
}

// B: one block per bucket: LDS hist -> scan -> rowptr slice (+self-loop) ->
// direct-global scatter via LDS cursors (R13 fast form; unsorted).
__global__ __launch_bounds__(512)
void build_scatter_kernel(const unsigned* __restrict__ pairs, const int* __restrict__ ecnt,
                          const int* __restrict__ ebase,
                          int* __restrict__ rowptr, int* __restrict__ srcs, int n, int nb) {
    __shared__ int lcnt[BKT_W];
    __shared__ int ssc[BKT_W];
    __shared__ int cur[BKT_W];
    int b = blockIdx.x;
    int lo = b * BKT_W;
    int hi = min(lo + BKT_W, n);
    int nrows = hi - lo;
    int cnt = ecnt[b], base = ebase[b];
    int s0 = base + lo;
    int t = threadIdx.x;
    lcnt[t] = 0;
    __syncthreads();
    for (int k = base + t; k < base + cnt; k += 512)
        atomicAdd(&lcnt[pairs[k] & 511u], 1);
    __syncthreads();
    int myc = lcnt[t];
    ssc[t] = myc;
    __syncthreads();
    #pragma unroll
    for (int off = 1; off < 512; off <<= 1) {
        int u = (t >= off) ? ssc[t - off] : 0;
        __syncthreads();
        ssc[t] += u;
        __syncthreads();
    }
    int lstart = (ssc[t] - myc) + t;
    if (t < nrows) {
        int rp = s0 + lstart;
        rowptr[lo + t] = rp;
        srcs[rp] = lo + t;     // self-loop
        cur[t] = rp + 1;
    }
    if (b == nb - 1 && t == 0) rowptr[n] = s0 + cnt + nrows;
    __syncthreads();
    for (int k = base + t; k < base + cnt; k += 512) {
        unsigned pr = pairs[k];
        int pos = atomicAdd(&cur[pr & 511u], 1);
        srcs[pos] = (int)(pr >> 9);
    }
}

// C: one wave per row: register bitonic sort of the row's srcs (<=64 elems,
// INT_MAX-padded). deg>64 fallback: lane-0 insertion sort (P~0 @ Poisson 17).
__global__ __launch_bounds__(256)
void sort_rows_kernel(const int* __restrict__ rowptr, int* __restrict__ srcs, int n) {
    int w = (int)((blockIdx.x * blockDim.x + threadIdx.x) >> 6);
    int lane = threadIdx.x & 63;
    if (w >= n) return;
    int st = rowptr[w], en = rowptr[w + 1];
    int len = en - st;
    if (len <= 1) return;
    if (len <= 64) {
        int v = (lane < len) ? srcs[st + lane] : 0x7fffffff;
        #pragma unroll
        for (int k = 2; k <= 64; k <<= 1) {
            #pragma unroll
            for (int j = k >> 1; j > 0; j >>= 1) {
                int partner = __shfl_xor(v, j);
                bool keepmin = ((lane & j) == 0) == ((lane & k) == 0);
                v = keepmin ? min(v, partner) : max(v, partner);
            }
        }
        if (lane < len) srcs[st + lane] = v;
    } else if (lane == 0) {
        for (int i = st + 1; i < en; i++) {
            int v = srcs[i], j = i - 1;
            while (j >= st && srcs[j] > v) { srcs[j + 1] = srcs[j]; j--; }
            srcs[j + 1] = v;
        }
    }
}

// Pack weights into MFMA B-frag layout (16x16x32 f16) -- device body
template<int NC, int K, bool DUAL>
__device__ inline void pack_w_dev(const float* __restrict__ W0, const float* __restrict__ W1,
                                  __half* __restrict__ Wp, int blk) {
    constexpr int KC = K / 32;
    constexpr int M = DUAL ? NC / 2 : NC;
    int idx = blk * 256 + (int)threadIdx.x;
    if (idx >= (NC / 16) * KC * 64) return;
    int lane = idx & 63;
    int c = (idx >> 6) % KC;
    int t = idx / (64 * KC);
    int col = t * 16 + (lane & 15);
    int k0 = c * 32 + (lane >> 4) * 8;
    __half tmp[8];
    #pragma unroll
    for (int e = 0; e < 8; e++) {
        int k = k0 + e;
        float v;
        if (DUAL) v = (col < M) ? W0[(size_t)k * M + col] : W1[(size_t)k * M + (col - M)];
        else      v = W0[(size_t)k * M + col];
        tmp[e] = __float2half(v);
    }
    *(uint4*)(Wp + (size_t)idx * 8) = *(uint4*)tmp;
}

// All 4 weight packs in one launch.
__global__ __launch_bounds__(256)
void pack_all_kernel(const float* __restrict__ Wl1, const float* __restrict__ Wr1,
                     const float* __restrict__ Wl2, const float* __restrict__ Wr2,
                     const float* __restrict__ We1, const float* __restrict__ We2,
                     __half* __restrict__ Wp1, __half* __restrict__ Wp2,
                     __half* __restrict__ We1p, __half* __restrict__ We2p) {
    int b = blockIdx.x;
    if (b < 16)      pack_w_dev<256, 128, true>(Wl1, Wr1, Wp1, b);
    else if (b < 24) pack_w_dev<128, 128, true>(Wl2, Wr2, Wp2, b - 16);
    else if (b < 26) pack_w_dev<64, 64, false>(We1, nullptr, We1p, b - 24);
    else             pack_w_dev<64, 64, false>(We2, nullptr, We2p, b - 26);
}

__device__ inline half8_t load_a8(const __half* p) { return *(const half8_t*)p; }
__device__ inline half8_t load_a8(const float* p) {
    float4 v0 = *(const float4*)p;
    float4 v1 = *(const float4*)(p + 4);
    half8_t r;
    r[0] = (_Float16)v0.x; r[1] = (_Float16)v0.y; r[2] = (_Float16)v0.z; r[3] = (_Float16)v0.w;
    r[4] = (_Float16)v1.x; r[5] = (_Float16)v1.y; r[6] = (_Float16)v1.z; r[7] = (_Float16)v1.w;
    return r;
}

// MFMA dual GEMM: one wave per (16-row tile, col quarter); no LDS.
template<int NC, int K, typename AT>
__global__ __launch_bounds__(256)
void gemm_mfma_kernel(const AT* __restrict__ A, const __half* __restrict__ Wp,
                      __half* __restrict__ Y0, __half* __restrict__ Y1, int n) {
    constexpr int KC = K / 32;
    constexpr int NT = NC / 16;
    constexpr int NTW = NT / 4;
    constexpr int M = NC / 2;
    int gw = (int)((blockIdx.x * 256 + threadIdx.x) >> 6);
    int lane = threadIdx.x & 63;
    int rt = gw >> 2;
    int wq = gw & 3;
    int row0 = rt * 16;
    if (row0 >= n) return;
    int arow = row0 + (lane & 15);
    int koff = (lane >> 4) * 8;
    half8_t af[KC];
    #pragma unroll
    for (int c = 0; c < KC; c++) {
        af[c] = (arow < n) ? load_a8(A + (size_t)arow * K + c * 32 + koff)
                           : half8_t{0, 0, 0, 0, 0, 0, 0, 0};
    }
    #pragma unroll
    for (int t4 = 0; t4 < NTW; t4++) {
        int t = wq * NTW + t4;
        f32x4_t acc = {0.f, 0.f, 0.f, 0.f};
        #pragma unroll
        for (int c = 0; c < KC; c++) {
            half8_t bf = *(const half8_t*)(Wp + (((size_t)t * KC + c) * 64 + lane) * 8);
            acc = __builtin_amdgcn_mfma_f32_16x16x32_f16(af[c], bf, acc, 0, 0, 0);
        }
        int col = t * 16 + (lane & 15);
        #pragma unroll
        for (int r = 0; r < 4; r++) {
            int row = row0 + (lane >> 4) * 4 + r;
            if (row < n) {
                __half v = __float2half(acc[r]);
                if (col < M) Y0[(size_t)row * M + col] = v;
                else         Y1[(size_t)row * M + (col - M)] = v;
            }
        }
    }
}

// 4 lanes per (node, head), heads interleaved. Single pass, DPP quad reduce,
// exp without max-subtraction. srcs per-row sorted -> lockstep L2 window.
// LS_MODE (H=1) fuses log_softmax.
template<int H, bool LS_MODE>
__global__ __launch_bounds__(256)
void node_agg_kernel(const __half* __restrict__ xl, const __half* __restrict__ xr,
                     const int* __restrict__ rowptr, const int* __restrict__ srcs,
                     const float* __restrict__ att, const float* __restrict__ bias,
                     __half* __restrict__ outh, float* __restrict__ outf, int n) {
    constexpr int HC = 64 * H;
    int g = (blockIdx.x * blockDim.x + threadIdx.x) >> 2;
    int lane = threadIdx.x & 3;
    if (g >= n * H) return;
    int node = g / H, head = g % H;
    int cb = head * 64 + lane * 16;

    const __half* xrp = xr + (size_t)node * HC + cb;
    uint4 ur0 = *(const uint4*)(xrp);
    uint4 ur1 = *(const uint4*)(xrp + 8);
    h2 r[8] = {bch2(ur0.x), bch2(ur0.y), bch2(ur0.z), bch2(ur0.w),
               bch2(ur1.x), bch2(ur1.y), bch2(ur1.z), bch2(ur1.w)};
    const float* ap = att + cb;
    h2 a[8];
    #pragma unroll
    for (int j = 0; j < 8; j++)
        a[j] = h2{(_Float16)ap[2 * j], (_Float16)ap[2 * j + 1]};
    const h2 k02 = {(_Float16)0.2f, (_Float16)0.2f};

    int start = rowptr[node], end = rowptr[node + 1];
    float d = 0.f;
    float acc[16];
    #pragma unroll
    for (int j = 0; j < 16; j++) acc[j] = 0.f;

    #pragma unroll 2
    for (int k = start; k < end; ++k) {
        int src = srcs[k];
        const __half* xlp = xl + (size_t)src * HC + cb;
        uint4 u0 = *(const uint4*)(xlp);
        uint4 u1 = *(const uint4*)(xlp + 8);
        h2 l[8] = {bch2(u0.x), bch2(u0.y), bch2(u0.z), bch2(u0.w),
                   bch2(u1.x), bch2(u1.y), bch2(u1.z), bch2(u1.w)};
        float pa = 0.f, pb = 0.f;
        #pragma unroll
        for (int j = 0; j < 4; j++) {
            h2 s = l[j] + r[j];
            s = __builtin_elementwise_max(s, s * k02);   // leaky_relu
            pa = __builtin_amdgcn_fdot2(s, a[j], pa, false);
        }
        #pragma unroll
        for (int j = 4; j < 8; j++) {
            h2 s = l[j] + r[j];
            s = __builtin_elementwise_max(s, s * k02);
            pb = __builtin_amdgcn_fdot2(s, a[j], pb, false);
        }
        float p = pa + pb;
        p += dpp_xor1(p);
        p += dpp_xor2(p);          // quad holds the head's logit
        float w = __expf(p);
        d += w;
        #pragma unroll
        for (int j = 0; j < 8; j++) {
            acc[2 * j]     += w * (float)l[j][0];
            acc[2 * j + 1] += w * (float)l[j][1];
        }
    }

    float inv = 1.f / (d + 1e-16f);
    const float* bp = bias + cb;
    if (!LS_MODE) {
        float o[16];
        #pragma unroll
        for (int j = 0; j < 16; j++) o[j] = fmaxf(acc[j] * inv + bp[j], 0.f);
        __half* op = outh + (size_t)node * HC + cb;
        uint4 w0, w1;
        __half2 t0 = __floats2half2_rn(o[0], o[1]),  t1 = __floats2half2_rn(o[2], o[3]);
        __half2 t2 = __floats2half2_rn(o[4], o[5]),  t3 = __floats2half2_rn(o[6], o[7]);
        __half2 t4 = __floats2half2_rn(o[8], o[9]),  t5 = __floats2half2_rn(o[10], o[11]);
        __half2 t6 = __floats2half2_rn(o[12], o[13]), t7 = __floats2half2_rn(o[14], o[15]);
        w0.x = *(unsigned int*)&t0; w0.y = *(unsigned int*)&t1;
        w0.z = *(unsigned int*)&t2; w0.w = *(unsigned int*)&t3;
        w1.x = *(unsigned int*)&t4; w1.y = *(unsigned int*)&t5;
        w1.z = *(unsigned int*)&t6; w1.w = *(unsigned int*)&t7;
        *(uint4*)(op) = w0;
        *(uint4*)(op + 8) = w1;
    } else {
        float v[16];
        #pragma unroll
        for (int j = 0; j < 16; j++) v[j] = acc[j] * inv + bp[j];
        float m = v[0];
        #pragma unroll
        for (int j = 1; j < 16; j++) m = fmaxf(m, v[j]);
        m = fmaxf(m, dpp_xor1(m));
        m = fmaxf(m, dpp_xor2(m));
        float s = 0.f;
        #pragma unroll
        for (int j = 0; j < 16; j++) s += __expf(v[j] - m);
        s += dpp_xor1(s);
        s += dpp_xor2(s);
        float lg = __logf(s);
        float ls[16];
        #pragma unroll
        for (int j = 0; j < 16; j++) ls[j] = v[j] - m - lg;
        float* of = outf + (size_t)node * HC + cb;
        #pragma unroll
        for (int q = 0; q < 4; q++)
            *(float4*)(of + q * 4) = make_float4(ls[q * 4], ls[q * 4 + 1], ls[q * 4 + 2], ls[q * 4 + 3]);
        __half* op = outh + (size_t)node * HC + cb;
        uint4 w0, w1;
        __half2 t0 = __floats2half2_rn(ls[0], ls[1]),  t1 = __floats2half2_rn(ls[2], ls[3]);
        __half2 t2 = __floats2half2_rn(ls[4], ls[5]),  t3 = __floats2half2_rn(ls[6], ls[7]);
        __half2 t4 = __floats2half2_rn(ls[8], ls[9]),  t5 = __floats2half2_rn(ls[10], ls[11]);
        __half2 t6 = __floats2half2_rn(ls[12], ls[13]), t7 = __floats2half2_rn(ls[14], ls[15]);
        w0.x = *(unsigned int*)&t0; w0.y = *(unsigned int*)&t1;
        w0.z = *(unsigned int*)&t2; w0.w = *(unsigned int*)&t3;
        w1.x = *(unsigned int*)&t4; w1.y = *(unsigned int*)&t5;
        w1.z = *(unsigned int*)&t6; w1.w = *(unsigned int*)&t7;
        *(uint4*)(op) = w0;
        *(uint4*)(op + 8) = w1;
    }
}

// Fused rule-net: T = relu(LS@We1+be1) (MFMA via LDS fp16 transpose),
// G = T@We2+be2, out = ls + sigmoid(G).
__global__ __launch_bounds__(256)
void gate_kernel(const float* __restrict__ lsf, const __half* __restrict__ lsh,
                 const __half* __restrict__ We1p, const float* __restrict__ be1,
                 const __half* __restrict__ We2p, const float* __restrict__ be2,
                 float* __restrict__ out, int n) {
    __shared__ _Float16 tls[4][16][64];
    int wid = threadIdx.x >> 6, lane = threadIdx.x & 63;
    int row0 = (blockIdx.x * 4 + wid) * 16;
    if (row0 >= n) return;
    int arow = row0 + (lane & 15);
    int koff = (lane >> 4) * 8;
    int colw = lane & 15;
    int rbase = (lane >> 4) * 4;

    half8_t af0 = (arow < n) ? *(const half8_t*)(lsh + (size_t)arow * 64 + koff)
                             : half8_t{0, 0, 0, 0, 0, 0, 0, 0};
    half8_t af1 = (arow < n) ? *(const half8_t*)(lsh + (size_t)arow * 64 + 32 + koff)
                             : half8_t{0, 0, 0, 0, 0, 0, 0, 0};
    #pragma unroll
    for (int t = 0; t < 4; t++) {
        f32x4_t acc = {0.f, 0.f, 0.f, 0.f};
        half8_t b0 = *(const half8_t*)(We1p + (((size_t)t * 2 + 0) * 64 + lane) * 8);
        half8_t b1 = *(const half8_t*)(We1p + (((size_t)t * 2 + 1) * 64 + lane) * 8);
        acc = __builtin_amdgcn_mfma_f32_16x16x32_f16(af0, b0, acc, 0, 0, 0);
        acc = __builtin_amdgcn_mfma_f32_16x16x32_f16(af1, b1, acc, 0, 0, 0);
        float bv = be1[t * 16 + colw];
        #pragma unroll
        for (int r = 0; r < 4; r++)
            tls[wid][rbase + r][t * 16 + colw] = (_Float16)fmaxf(acc[r] + bv, 0.f);
    }
    half8_t tf0 = *(const half8_t*)&tls[wid][lane & 15][koff];
    half8_t tf1 = *(const half8_t*)&tls[wid][lane & 15][32 + koff];
    #pragma unroll
    for (int t = 0; t < 4; t++) {
        f32x4_t acc = {0.f, 0.f, 0.f, 0.f};
        half8_t b0 = *(const half8_t*)(We2p + (((size_t)t * 2 + 0) * 64 + lane) * 8);
        half8_t b1 = *(const half8_t*)(We2p + (((size_t)t * 2 + 1) * 64 + lane) * 8);
        acc = __builtin_amdgcn_mfma_f32_16x16x32_f16(tf0, b0, acc, 0, 0, 0);
        acc = __builtin_amdgcn_mfma_f32_16x16x32_f16(tf1, b1, acc, 0, 0, 0);
        int col = t * 16 + colw;
        float bv = be2[col];
        #pragma unroll
        for (int r = 0; r < 4; r++) {
            int row = row0 + rbase + r;
            if (row < n) {
                float g = 1.f / (1.f + __expf(-(acc[r] + bv)));
                out[(size_t)row * 64 + col] = lsf[(size_t)row * 64 + col] + g;
            }
        }
    }
}

extern "C" void kernel_launch(void* const* d_in, const int* in_sizes, int n_in,
                              void* d_out, int out_size, void* d_ws, size_t ws_size,
                              hipStream_t stream) {
    const float* x    = (const float*)d_in[0];
    const int*   ei   = (const int*)d_in[1];
    const float* Wl1  = (const float*)d_in[2];
    const float* Wr1  = (const float*)d_in[3];
    const float* att1 = (const float*)d_in[4];
    const float* b1   = (const float*)d_in[5];
    const float* Wl2  = (const float*)d_in[6];
    const float* Wr2  = (const float*)d_in[7];
    const float* att2 = (const float*)d_in[8];
    const float* b2   = (const float*)d_in[9];
    const float* We1  = (const float*)d_in[10];
    const float* be1  = (const float*)d_in[11];
    const float* We2  = (const float*)d_in[12];
    const float* be2  = (const float*)d_in[13];
    float* out = (float*)d_out;

    const int n  = in_sizes[0] / 128;
    const int E  = in_sizes[1] / 2;
    const int ET = E + n;
    const int nb = (n + BKT_W - 1) / BKT_W;

    float* ws = (float*)d_ws;
    size_t o = 0;
    __half* xl1 = (__half*)(ws + o); o += (size_t)n * 64;   // [n,128] fp16
    __half* xr1 = (__half*)(ws + o); o += (size_t)n * 64;   // [n,128] fp16
    __half* h1h = (__half*)(ws + o); o += (size_t)n * 64;   // h1 fp16 [n,128]
    float*  v2  = ws + o;            o += (size_t)n * 64;   // ls fp32 [n,64]
    __half* lsh = (__half*)(ws + o); o += (size_t)n * 32;   // ls fp16 [n,64]
    __half* Wp1 = (__half*)(ws + o); o += 16384;
    __half* Wp2 = (__half*)(ws + o); o += 8192;
    __half* We1p = (__half*)(ws + o); o += 2048;
    __half* We2p = (__half*)(ws + o); o += 2048;
    int* rowptr   = (int*)(ws + o); o += (size_t)(n + 1);
    int* srcs     = (int*)(ws + o); o += (size_t)ET;
    unsigned* pairs = (unsigned*)(ws + o); o += (size_t)E;  // packed src<<9|dstlo
    int* ecnt     = (int*)(ws + o); o += 128;
    int* ebase    = (int*)(ws + o); o += 128;
    int* bcur     = (int*)(ws + o); o += 128;
    __half* xl2 = xl1;                     // [n,64] fp16 (reuses dead xl1 region)
    __half* xr2 = xl1 + (size_t)n * 64;
    float* lsf = v2;

    const int BS = 256;
    auto blocks = [](long long t, int bs) { return (int)((t + bs - 1) / bs); };

    // ---- CSR build (by dst), atomic-free per node; rows sorted by src ----
    fill_int_kernel<<<1, 128, 0, stream>>>(ecnt, 0, 128);
    bkt_hist_kernel<<<128, 1024, 0, stream>>>(ei, ecnt, E, nb);
    bkt_scan_kernel<<<1, 128, 0, stream>>>(ecnt, ebase, bcur, nb);
    bucket_pass_kernel<<<blocks(E, 1024 * PA_EPT), 1024, 0, stream>>>(ei, E, bcur, pairs, nb);
    build_scatter_kernel<<<nb, 512, 0, stream>>>(pairs, ecnt, ebase, rowptr, srcs, n, nb);
    sort_rows_kernel<<<blocks((long long)n * 64, BS), BS, 0, stream>>>(rowptr, srcs, n);

    // ---- all weight packs, one launch ----
    pack_all_kernel<<<28, 256, 0, stream>>>(Wl1, Wr1, Wl2, Wr2, We1, We2,
                                            Wp1, Wp2, We1p, We2p);

    // ---- layer 1 (gemm reads fp32 x directly) ----
    const int rt = (n + 15) / 16;          // row tiles
    gemm_mfma_kernel<256, 128, float><<<rt, 256, 0, stream>>>(x, Wp1, xl1, xr1, n);
    node_agg_kernel<2, false><<<blocks((long long)n * 2 * 4, BS), BS, 0, stream>>>(
        xl1, xr1, rowptr, srcs, att1, b1, h1h, nullptr, n);

    // ---- layer 2 (log_softmax fused into agg) ----
    gemm_mfma_kernel<128, 128, __half><<<rt, 256, 0, stream>>>(h1h, Wp2, xl2, xr2, n);
    node_agg_kernel<1, true><<<blocks((long long)n * 4, BS), BS, 0, stream>>>(
        xl2, xr2, rowptr, srcs, att2, b2, lsh, v2, n);

    // ---- finalize: fused MFMA rule-net ----
    gate_kernel<<<(n + 63) / 64, BS, 0, stream>>>(lsf, lsh, We1p, be1, We2p, be2, out, n);
}

// Round 17
// 165.212 us; speedup vs baseline: 1.2377x; 1.0413x over previous
//
#include <hip/hip_runtime.h>
#include <hip/hip_bf16.h>
#include <hip/hip_fp16.h>
#include <math.h>

// ---------------------------------------------------------------------------
// GATv2 x2 + log_softmax + gated rule-net.
// R16: consolidation to best measured config (R13 structure + uint32-packed
// pairs). sort_rows REVERTED: R15 showed sorted adjacency gains ~0 (R14's
// "+20us" was mis-attributed to build_scatter cost). node_agg is at its
// compulsory-traffic floor: 8 XCDs x 12.8MB table ~ 100MB ~ measured FETCH.
// ---------------------------------------------------------------------------

typedef _Float16 h2 __attribute__((ext_vector_type(2)));
typedef _Float16 half8_t __attribute__((ext_vector_type(8)));
typedef float f32x4_t __attribute__((ext_vector_type(4)));
union H2U { unsigned int u; h2 h; };
__device__ inline h2 bch2(unsigned int x) { H2U t; t.u = x; return t.h; }

constexpr int BKT_W = 512;   // dsts per bucket
constexpr int PA_EPT = 8;    // edges per thread, bucket_pass

__device__ inline float dpp_xor1(float x) {
    int v = __builtin_amdgcn_mov_dpp(__builtin_bit_cast(int, x), 0xB1, 0xF, 0xF, true);
    return __builtin_bit_cast(float, v);
}
__device__ inline float dpp_xor2(float x) {
    int v = __builtin_amdgcn_mov_dpp(__builtin_bit_cast(int, x), 0x4E, 0xF, 0xF, true);
    return __builtin_bit_cast(float, v);
}

__global__ void fill_int_kernel(int* __restrict__ p, int v, int count) {
    int i = blockIdx.x * blockDim.x + threadIdx.x;
    if (i < count) p[i] = v;
}

// A1: edges-per-bucket histogram (LDS, one global atomic per block-bin)
__global__ __launch_bounds__(1024)
void bkt_hist_kernel(const int* __restrict__ ei, int* __restrict__ ecnt, int E, int nb) {
    __shared__ int lh[128];
    if (threadIdx.x < 128) lh[threadIdx.x] = 0;
    __syncthreads();
    for (int e = blockIdx.x * blockDim.x + threadIdx.x; e < E; e += gridDim.x * blockDim.x)
        atomicAdd(&lh[ei[E + e] >> 9], 1);
    __syncthreads();
    if (threadIdx.x < (unsigned)nb && lh[threadIdx.x])
        atomicAdd(&ecnt[threadIdx.x], lh[threadIdx.x]);
}

// A2: exclusive scan of <=128 bucket counts -> ebase; seed bcur.
__global__ __launch_bounds__(128)
void bkt_scan_kernel(const int* __restrict__ ecnt, int* __restrict__ ebase,
                     int* __restrict__ bcur, int nb) {
    __shared__ int s[128];
    int t = threadIdx.x;
    int v = (t < nb) ? ecnt[t] : 0;
    s[t] = v;
    __syncthreads();
    #pragma unroll
    for (int off = 1; off < 128; off <<= 1) {
        int u = (t >= off) ? s[t - off] : 0;
        __syncthreads();
        s[t] += u;
        __syncthreads();
    }
    if (t < nb) { int b = s[t] - v; ebase[t] = b; bcur[t] = b; }
}

// A3: partition edges into buckets (LDS ranks); pairs packed src<<9 | dst&511.
__global__ __launch_bounds__(1024)
void bucket_pass_kernel(const int* __restrict__ ei, int E,
                        int* __restrict__ bcur, unsigned* __restrict__ pairs, int nb) {
    __shared__ int lhist[128];
    __shared__ int lbase[128];
    int e0 = blockIdx.x * (1024 * PA_EPT);
    if (threadIdx.x < 128) lhist[threadIdx.x] = 0;
    __syncthreads();
    int mysrc[PA_EPT], mydst[PA_EPT], myrank[PA_EPT];
    #pragma unroll
    for (int j = 0; j < PA_EPT; j++) {
        int e = e0 + j * 1024 + threadIdx.x;
        if (e < E) {
            mysrc[j] = ei[e];
            mydst[j] = ei[E + e];
            myrank[j] = atomicAdd(&lhist[mydst[j] >> 9], 1);
        } else mydst[j] = -1;
    }
    __syncthreads();
    if (threadIdx.x < (unsigned)nb && lhist[threadIdx.x] > 0)
        lbase[threadIdx.x] = atomicAdd(&bcur[threadIdx.x], lhist[threadIdx.x]);
    __syncthreads();
    #pragma unroll
    for (int j = 0; j < PA_EPT; j++) {
        if (mydst[j] >= 0) {
            int b = mydst[j] >> 9;
            pairs[(size_t)lbase[b] + myrank[j]] =
                ((unsigned)mysrc[j] << 9) | (unsigned)(mydst[j] & 511);
        }
    }
}

// B: one block per bucket: LDS hist -> scan -> rowptr slice (+self-loop) ->
// direct-global scatter via LDS cursors. Single-XCD full-line writes.
__global__ __launch_bounds__(512)
void build_scatter_kernel(const unsigned* __restrict__ pairs, const int* __restrict__ ecnt,
                          const int* __restrict__ ebase,
                          int* __restrict__ rowptr, int* __restrict__ srcs, int n, int nb) {
    __shared__ int lcnt[BKT_W];
    __shared__ int ssc[BKT_W];
    __shared__ int cur[BKT_W];
    int b = blockIdx.x;
    int lo = b * BKT_W;
    int hi = min(lo + BKT_W, n);
    int nrows = hi - lo;
    int cnt = ecnt[b], base = ebase[b];
    int s0 = base + lo;
    int t = threadIdx.x;
    lcnt[t] = 0;
    __syncthreads();
    for (int k = base + t; k < base + cnt; k += 512)
        atomicAdd(&lcnt[pairs[k] & 511u], 1);
    __syncthreads();
    int myc = lcnt[t];
    ssc[t] = myc;
    __syncthreads();
    #pragma unroll
    for (int off = 1; off < 512; off <<= 1) {
        int u = (t >= off) ? ssc[t - off] : 0;
        __syncthreads();
        ssc[t] += u;
        __syncthreads();
    }
    int lstart = (ssc[t] - myc) + t;
    if (t < nrows) {
        int rp = s0 + lstart;
        rowptr[lo + t] = rp;
        srcs[rp] = lo + t;     // self-loop
        cur[t] = rp + 1;
    }
    if (b == nb - 1 && t == 0) rowptr[n] = s0 + cnt + nrows;
    __syncthreads();
    for (int k = base + t; k < base + cnt; k += 512) {
        unsigned pr = pairs[k];
        int pos = atomicAdd(&cur[pr & 511u], 1);
        srcs[pos] = (int)(pr >> 9);
    }
}

// Pack weights into MFMA B-frag layout (16x16x32 f16) -- device body
template<int NC, int K, bool DUAL>
__device__ inline void pack_w_dev(const float* __restrict__ W0, const float* __restrict__ W1,
                                  __half* __restrict__ Wp, int blk) {
    constexpr int KC = K / 32;
    constexpr int M = DUAL ? NC / 2 : NC;
    int idx = blk * 256 + (int)threadIdx.x;
    if (idx >= (NC / 16) * KC * 64) return;
    int lane = idx & 63;
    int c = (idx >> 6) % KC;
    int t = idx / (64 * KC);
    int col = t * 16 + (lane & 15);
    int k0 = c * 32 + (lane >> 4) * 8;
    __half tmp[8];
    #pragma unroll
    for (int e = 0; e < 8; e++) {
        int k = k0 + e;
        float v;
        if (DUAL) v = (col < M) ? W0[(size_t)k * M + col] : W1[(size_t)k * M + (col - M)];
        else      v = W0[(size_t)k * M + col];
        tmp[e] = __float2half(v);
    }
    *(uint4*)(Wp + (size_t)idx * 8) = *(uint4*)tmp;
}

// All 4 weight packs in one launch.
__global__ __launch_bounds__(256)
void pack_all_kernel(const float* __restrict__ Wl1, const float* __restrict__ Wr1,
                     const float* __restrict__ Wl2, const float* __restrict__ Wr2,
                     const float* __restrict__ We1, const float* __restrict__ We2,
                     __half* __restrict__ Wp1, __half* __restrict__ Wp2,
                     __half* __restrict__ We1p, __half* __restrict__ We2p) {
    int b = blockIdx.x;
    if (b < 16)      pack_w_dev<256, 128, true>(Wl1, Wr1, Wp1, b);
    else if (b < 24) pack_w_dev<128, 128, true>(Wl2, Wr2, Wp2, b - 16);
    else if (b < 26) pack_w_dev<64, 64, false>(We1, nullptr, We1p, b - 24);
    else             pack_w_dev<64, 64, false>(We2, nullptr, We2p, b - 26);
}

__device__ inline half8_t load_a8(const __half* p) { return *(const half8_t*)p; }
__device__ inline half8_t load_a8(const float* p) {
    float4 v0 = *(const float4*)p;
    float4 v1 = *(const float4*)(p + 4);
    half8_t r;
    r[0] = (_Float16)v0.x; r[1] = (_Float16)v0.y; r[2] = (_Float16)v0.z; r[3] = (_Float16)v0.w;
    r[4] = (_Float16)v1.x; r[5] = (_Float16)v1.y; r[6] = (_Float16)v1.z; r[7] = (_Float16)v1.w;
    return r;
}

// MFMA dual GEMM: one wave per (16-row tile, col quarter); no LDS.
template<int NC, int K, typename AT>
__global__ __launch_bounds__(256)
void gemm_mfma_kernel(const AT* __restrict__ A, const __half* __restrict__ Wp,
                      __half* __restrict__ Y0, __half* __restrict__ Y1, int n) {
    constexpr int KC = K / 32;
    constexpr int NT = NC / 16;
    constexpr int NTW = NT / 4;
    constexpr int M = NC / 2;
    int gw = (int)((blockIdx.x * 256 + threadIdx.x) >> 6);
    int lane = threadIdx.x & 63;
    int rt = gw >> 2;
    int wq = gw & 3;
    int row0 = rt * 16;
    if (row0 >= n) return;
    int arow = row0 + (lane & 15);
    int koff = (lane >> 4) * 8;
    half8_t af[KC];
    #pragma unroll
    for (int c = 0; c < KC; c++) {
        af[c] = (arow < n) ? load_a8(A + (size_t)arow * K + c * 32 + koff)
                           : half8_t{0, 0, 0, 0, 0, 0, 0, 0};
    }
    #pragma unroll
    for (int t4 = 0; t4 < NTW; t4++) {
        int t = wq * NTW + t4;
        f32x4_t acc = {0.f, 0.f, 0.f, 0.f};
        #pragma unroll
        for (int c = 0; c < KC; c++) {
            half8_t bf = *(const half8_t*)(Wp + (((size_t)t * KC + c) * 64 + lane) * 8);
            acc = __builtin_amdgcn_mfma_f32_16x16x32_f16(af[c], bf, acc, 0, 0, 0);
        }
        int col = t * 16 + (lane & 15);
        #pragma unroll
        for (int r = 0; r < 4; r++) {
            int row = row0 + (lane >> 4) * 4 + r;
            if (row < n) {
                __half v = __float2half(acc[r]);
                if (col < M) Y0[(size_t)row * M + col] = v;
                else         Y1[(size_t)row * M + (col - M)] = v;
            }
        }
    }
}

// 4 lanes per (node, head), heads interleaved. Single pass, DPP quad reduce,
// exp without max-subtraction. LS_MODE (H=1) fuses log_softmax.
template<int H, bool LS_MODE>
__global__ __launch_bounds__(256)
void node_agg_kernel(const __half* __restrict__ xl, const __half* __restrict__ xr,
                     const int* __restrict__ rowptr, const int* __restrict__ srcs,
                     const float* __restrict__ att, const float* __restrict__ bias,
                     __half* __restrict__ outh, float* __restrict__ outf, int n) {
    constexpr int HC = 64 * H;
    int g = (blockIdx.x * blockDim.x + threadIdx.x) >> 2;
    int lane = threadIdx.x & 3;
    if (g >= n * H) return;
    int node = g / H, head = g % H;
    int cb = head * 64 + lane * 16;

    const __half* xrp = xr + (size_t)node * HC + cb;
    uint4 ur0 = *(const uint4*)(xrp);
    uint4 ur1 = *(const uint4*)(xrp + 8);
    h2 r[8] = {bch2(ur0.x), bch2(ur0.y), bch2(ur0.z), bch2(ur0.w),
               bch2(ur1.x), bch2(ur1.y), bch2(ur1.z), bch2(ur1.w)};
    const float* ap = att + cb;
    h2 a[8];
    #pragma unroll
    for (int j = 0; j < 8; j++)
        a[j] = h2{(_Float16)ap[2 * j], (_Float16)ap[2 * j + 1]};
    const h2 k02 = {(_Float16)0.2f, (_Float16)0.2f};

    int start = rowptr[node], end = rowptr[node + 1];
    float d = 0.f;
    float acc[16];
    #pragma unroll
    for (int j = 0; j < 16; j++) acc[j] = 0.f;

    #pragma unroll 2
    for (int k = start; k < end; ++k) {
        int src = srcs[k];
        const __half* xlp = xl + (size_t)src * HC + cb;
        uint4 u0 = *(const uint4*)(xlp);
        uint4 u1 = *(const uint4*)(xlp + 8);
        h2 l[8] = {bch2(u0.x), bch2(u0.y), bch2(u0.z), bch2(u0.w),
                   bch2(u1.x), bch2(u1.y), bch2(u1.z), bch2(u1.w)};
        float pa = 0.f, pb = 0.f;
        #pragma unroll
        for (int j = 0; j < 4; j++) {
            h2 s = l[j] + r[j];
            s = __builtin_elementwise_max(s, s * k02);   // leaky_relu
            pa = __builtin_amdgcn_fdot2(s, a[j], pa, false);
        }
        #pragma unroll
        for (int j = 4; j < 8; j++) {
            h2 s = l[j] + r[j];
            s = __builtin_elementwise_max(s, s * k02);
            pb = __builtin_amdgcn_fdot2(s, a[j], pb, false);
        }
        float p = pa + pb;
        p += dpp_xor1(p);
        p += dpp_xor2(p);          // quad holds the head's logit
        float w = __expf(p);
        d += w;
        #pragma unroll
        for (int j = 0; j < 8; j++) {
            acc[2 * j]     += w * (float)l[j][0];
            acc[2 * j + 1] += w * (float)l[j][1];
        }
    }

    float inv = 1.f / (d + 1e-16f);
    const float* bp = bias + cb;
    if (!LS_MODE) {
        float o[16];
        #pragma unroll
        for (int j = 0; j < 16; j++) o[j] = fmaxf(acc[j] * inv + bp[j], 0.f);
        __half* op = outh + (size_t)node * HC + cb;
        uint4 w0, w1;
        __half2 t0 = __floats2half2_rn(o[0], o[1]),  t1 = __floats2half2_rn(o[2], o[3]);
        __half2 t2 = __floats2half2_rn(o[4], o[5]),  t3 = __floats2half2_rn(o[6], o[7]);
        __half2 t4 = __floats2half2_rn(o[8], o[9]),  t5 = __floats2half2_rn(o[10], o[11]);
        __half2 t6 = __floats2half2_rn(o[12], o[13]), t7 = __floats2half2_rn(o[14], o[15]);
        w0.x = *(unsigned int*)&t0; w0.y = *(unsigned int*)&t1;
        w0.z = *(unsigned int*)&t2; w0.w = *(unsigned int*)&t3;
        w1.x = *(unsigned int*)&t4; w1.y = *(unsigned int*)&t5;
        w1.z = *(unsigned int*)&t6; w1.w = *(unsigned int*)&t7;
        *(uint4*)(op) = w0;
        *(uint4*)(op + 8) = w1;
    } else {
        float v[16];
        #pragma unroll
        for (int j = 0; j < 16; j++) v[j] = acc[j] * inv + bp[j];
        float m = v[0];
        #pragma unroll
        for (int j = 1; j < 16; j++) m = fmaxf(m, v[j]);
        m = fmaxf(m, dpp_xor1(m));
        m = fmaxf(m, dpp_xor2(m));
        float s = 0.f;
        #pragma unroll
        for (int j = 0; j < 16; j++) s += __expf(v[j] - m);
        s += dpp_xor1(s);
        s += dpp_xor2(s);
        float lg = __logf(s);
        float ls[16];
        #pragma unroll
        for (int j = 0; j < 16; j++) ls[j] = v[j] - m - lg;
        float* of = outf + (size_t)node * HC + cb;
        #pragma unroll
        for (int q = 0; q < 4; q++)
            *(float4*)(of + q * 4) = make_float4(ls[q * 4], ls[q * 4 + 1], ls[q * 4 + 2], ls[q * 4 + 3]);
        __half* op = outh + (size_t)node * HC + cb;
        uint4 w0, w1;
        __half2 t0 = __floats2half2_rn(ls[0], ls[1]),  t1 = __floats2half2_rn(ls[2], ls[3]);
        __half2 t2 = __floats2half2_rn(ls[4], ls[5]),  t3 = __floats2half2_rn(ls[6], ls[7]);
        __half2 t4 = __floats2half2_rn(ls[8], ls[9]),  t5 = __floats2half2_rn(ls[10], ls[11]);
        __half2 t6 = __floats2half2_rn(ls[12], ls[13]), t7 = __floats2half2_rn(ls[14], ls[15]);
        w0.x = *(unsigned int*)&t0; w0.y = *(unsigned int*)&t1;
        w0.z = *(unsigned int*)&t2; w0.w = *(unsigned int*)&t3;
        w1.x = *(unsigned int*)&t4; w1.y = *(unsigned int*)&t5;
        w1.z = *(unsigned int*)&t6; w1.w = *(unsigned int*)&t7;
        *(uint4*)(op) = w0;
        *(uint4*)(op + 8) = w1;
    }
}

// Fused rule-net: T = relu(LS@We1+be1) (MFMA via LDS fp16 transpose),
// G = T@We2+be2, out = ls + sigmoid(G).
__global__ __launch_bounds__(256)
void gate_kernel(const float* __restrict__ lsf, const __half* __restrict__ lsh,
                 const __half* __restrict__ We1p, const float* __restrict__ be1,
                 const __half* __restrict__ We2p, const float* __restrict__ be2,
                 float* __restrict__ out, int n) {
    __shared__ _Float16 tls[4][16][64];
    int wid = threadIdx.x >> 6, lane = threadIdx.x & 63;
    int row0 = (blockIdx.x * 4 + wid) * 16;
    if (row0 >= n) return;
    int arow = row0 + (lane & 15);
    int koff = (lane >> 4) * 8;
    int colw = lane & 15;
    int rbase = (lane >> 4) * 4;

    half8_t af0 = (arow < n) ? *(const half8_t*)(lsh + (size_t)arow * 64 + koff)
                             : half8_t{0, 0, 0, 0, 0, 0, 0, 0};
    half8_t af1 = (arow < n) ? *(const half8_t*)(lsh + (size_t)arow * 64 + 32 + koff)
                             : half8_t{0, 0, 0, 0, 0, 0, 0, 0};
    #pragma unroll
    for (int t = 0; t < 4; t++) {
        f32x4_t acc = {0.f, 0.f, 0.f, 0.f};
        half8_t b0 = *(const half8_t*)(We1p + (((size_t)t * 2 + 0) * 64 + lane) * 8);
        half8_t b1 = *(const half8_t*)(We1p + (((size_t)t * 2 + 1) * 64 + lane) * 8);
        acc = __builtin_amdgcn_mfma_f32_16x16x32_f16(af0, b0, acc, 0, 0, 0);
        acc = __builtin_amdgcn_mfma_f32_16x16x32_f16(af1, b1, acc, 0, 0, 0);
        float bv = be1[t * 16 + colw];
        #pragma unroll
        for (int r = 0; r < 4; r++)
            tls[wid][rbase + r][t * 16 + colw] = (_Float16)fmaxf(acc[r] + bv, 0.f);
    }
    half8_t tf0 = *(const half8_t*)&tls[wid][lane & 15][koff];
    half8_t tf1 = *(const half8_t*)&tls[wid][lane & 15][32 + koff];
    #pragma unroll
    for (int t = 0; t < 4; t++) {
        f32x4_t acc = {0.f, 0.f, 0.f, 0.f};
        half8_t b0 = *(const half8_t*)(We2p + (((size_t)t * 2 + 0) * 64 + lane) * 8);
        half8_t b1 = *(const half8_t*)(We2p + (((size_t)t * 2 + 1) * 64 + lane) * 8);
        acc = __builtin_amdgcn_mfma_f32_16x16x32_f16(tf0, b0, acc, 0, 0, 0);
        acc = __builtin_amdgcn_mfma_f32_16x16x32_f16(tf1, b1, acc, 0, 0, 0);
        int col = t * 16 + colw;
        float bv = be2[col];
        #pragma unroll
        for (int r = 0; r < 4; r++) {
            int row = row0 + rbase + r;
            if (row < n) {
                float g = 1.f / (1.f + __expf(-(acc[r] + bv)));
                out[(size_t)row * 64 + col] = lsf[(size_t)row * 64 + col] + g;
            }
        }
    }
}

extern "C" void kernel_launch(void* const* d_in, const int* in_sizes, int n_in,
                              void* d_out, int out_size, void* d_ws, size_t ws_size,
                              hipStream_t stream) {
    const float* x    = (const float*)d_in[0];
    const int*   ei   = (const int*)d_in[1];
    const float* Wl1  = (const float*)d_in[2];
    const float* Wr1  = (const float*)d_in[3];
    const float* att1 = (const float*)d_in[4];
    const float* b1   = (const float*)d_in[5];
    const float* Wl2  = (const float*)d_in[6];
    const float* Wr2  = (const float*)d_in[7];
    const float* att2 = (const float*)d_in[8];
    const float* b2   = (const float*)d_in[9];
    const float* We1  = (const float*)d_in[10];
    const float* be1  = (const float*)d_in[11];
    const float* We2  = (const float*)d_in[12];
    const float* be2  = (const float*)d_in[13];
    float* out = (float*)d_out;

    const int n  = in_sizes[0] / 128;
    const int E  = in_sizes[1] / 2;
    const int ET = E + n;
    const int nb = (n + BKT_W - 1) / BKT_W;

    float* ws = (float*)d_ws;
    size_t o = 0;
    __half* xl1 = (__half*)(ws + o); o += (size_t)n * 64;   // [n,128] fp16
    __half* xr1 = (__half*)(ws + o); o += (size_t)n * 64;   // [n,128] fp16
    __half* h1h = (__half*)(ws + o); o += (size_t)n * 64;   // h1 fp16 [n,128]
    float*  v2  = ws + o;            o += (size_t)n * 64;   // ls fp32 [n,64]
    __half* lsh = (__half*)(ws + o); o += (size_t)n * 32;   // ls fp16 [n,64]
    __half* Wp1 = (__half*)(ws + o); o += 16384;
    __half* Wp2 = (__half*)(ws + o); o += 8192;
    __half* We1p = (__half*)(ws + o); o += 2048;
    __half* We2p = (__half*)(ws + o); o += 2048;
    int* rowptr   = (int*)(ws + o); o += (size_t)(n + 1);
    int* srcs     = (int*)(ws + o); o += (size_t)ET;
    unsigned* pairs = (unsigned*)(ws + o); o += (size_t)E;  // packed src<<9|dstlo
    int* ecnt     = (int*)(ws + o); o += 128;
    int* ebase    = (int*)(ws + o); o += 128;
    int* bcur     = (int*)(ws + o); o += 128;
    __half* xl2 = xl1;                     // [n,64] fp16 (reuses dead xl1 region)
    __half* xr2 = xl1 + (size_t)n * 64;
    float* lsf = v2;

    const int BS = 256;
    auto blocks = [](long long t, int bs) { return (int)((t + bs - 1) / bs); };

    // ---- CSR build (by dst), atomic-free per node ----
    fill_int_kernel<<<1, 128, 0, stream>>>(ecnt, 0, 128);
    bkt_hist_kernel<<<128, 1024, 0, stream>>>(ei, ecnt, E, nb);
    bkt_scan_kernel<<<1, 128, 0, stream>>>(ecnt, ebase, bcur, nb);
    bucket_pass_kernel<<<blocks(E, 1024 * PA_EPT), 1024, 0, stream>>>(ei, E, bcur, pairs, nb);
    build_scatter_kernel<<<nb, 512, 0, stream>>>(pairs, ecnt, ebase, rowptr, srcs, n, nb);

    // ---- all weight packs, one launch ----
    pack_all_kernel<<<28, 256, 0, stream>>>(Wl1, Wr1, Wl2, Wr2, We1, We2,
                                            Wp1, Wp2, We1p, We2p);

    // ---- layer 1 (gemm reads fp32 x directly) ----
    const int rt = (n + 15) / 16;          // row tiles
    gemm_mfma_kernel<256, 128, float><<<rt, 256, 0, stream>>>(x, Wp1, xl1, xr1, n);
    node_agg_kernel<2, false><<<blocks((long long)n * 2 * 4, BS), BS, 0, stream>>>(
        xl1, xr1, rowptr, srcs, att1, b1, h1h, nullptr, n);

    // ---- layer 2 (log_softmax fused into agg) ----
    gemm_mfma_kernel<128, 128, __half><<<rt, 256, 0, stream>>>(h1h, Wp2, xl2, xr2, n);
    node_agg_kernel<1, true><<<blocks((long long)n * 4, BS), BS, 0, stream>>>(
        xl2, xr2, rowptr, srcs, att2, b2, lsh, v2, n);

    // ---- finalize: fused MFMA rule-net ----
    gate_kernel<<<(n + 63) / 64, BS, 0, stream>>>(lsf, lsh, We1p, be1, We2p, be2, out, n);
}